// Round 1
// baseline (380.253 us; speedup 1.0000x reference)
//
#include <hip/hip_runtime.h>
#include <hip/hip_bf16.h>
#include <math.h>

// ---------- types ----------
typedef __attribute__((ext_vector_type(8))) __bf16 bf16x8;
typedef __attribute__((ext_vector_type(4))) float f32x4;

// fp32 -> bf16 round-to-nearest-even (bit trick)
__device__ __forceinline__ unsigned short f2bf(float f) {
    union { float f; unsigned u; } v; v.f = f;
    unsigned r = v.u + 0x7fffu + ((v.u >> 16) & 1u);
    return (unsigned short)(r >> 16);
}
// pack two fp32 into one dword of two bf16 (lo, hi)
__device__ __forceinline__ unsigned int pk(float a, float b) {
    union { float f; unsigned u; } x, y; x.f = a; y.f = b;
    unsigned ra = (x.u + 0x7fffu + ((x.u >> 16) & 1u)) >> 16;
    unsigned rb = (y.u + 0x7fffu + ((y.u >> 16) & 1u)) & 0xffff0000u;
    return ra | rb;
}

// ---------- weight transpose + fp32->bf16 convert ----------
// dst[n*K + k] = bf16(src[k*N + n]);  64x64 LDS tiles, coalesced both sides.
struct TPArgs {
    const float* src[5];
    unsigned short* dst[5];
    int K[5];
    int N[5];
    int tstart[6];
};

__global__ __launch_bounds__(256) void transpose_convert(TPArgs a) {
    __shared__ float tile[64][65];
    int bx = blockIdx.x;
    int m = 0;
    while (bx >= a.tstart[m + 1]) m++;
    const float* src = a.src[m];
    unsigned short* dst = a.dst[m];
    const int K = a.K[m], N = a.N[m];
    const int t = bx - a.tstart[m];
    const int ntn = N >> 6;
    const int tk = t / ntn, tn = t % ntn;
    const int c = threadIdx.x & 63, r0 = threadIdx.x >> 6;
    #pragma unroll
    for (int r = r0; r < 64; r += 4)
        tile[r][c] = src[(size_t)(tk * 64 + r) * N + tn * 64 + c];
    __syncthreads();
    #pragma unroll
    for (int r = r0; r < 64; r += 4)
        dst[(size_t)(tn * 64 + r) * K + tk * 64 + c] = f2bf(tile[c][r]);
}

// ---------- leftover passthrough copy ----------
// out[b, 24+l, :] = fv[b, leftover_idx[l], :]  (not-fields overwritten later)
__global__ __launch_bounds__(256) void copy_leftover(const float* __restrict__ fv,
                                                     const int* __restrict__ lidx,
                                                     float* __restrict__ out) {
    int t = blockIdx.x * 256 + threadIdx.x;   // one float4 each
    int c4 = t & 127;          // 128 float4 per 512-row
    int l  = (t >> 7) & 15;
    int b  = t >> 11;
    const float4 v = *(const float4*)(fv + ((size_t)b * 64 + lidx[l]) * 512 + c4 * 4);
    *(float4*)(out + ((size_t)b * 40 + 24 + l) * 512 + c4 * 4) = v;
}

// ---------- fused GEMM ----------
// C[M,512] = act(A[M,K] @ W[K,512] + bias)
// SRCM: 0 = A row m is concat(fv[b,pair[p][0]], fv[b,pair[p][1]]) fp32 (m=b*P+p)
//       1 = A row m is fv[b, not_idx[i]] fp32 (m=b*8+i)
//       2 = A is plain bf16 [M,K] (hidden)
// EPIM: 0 = ReLU -> bf16 hidden[m*512+n]
//       1 = +bias -> fp32 out[(b*40+QBASE+p)*512+n]
//       2 = tanh  -> fp32 out[(b*40+q)*512+n], q = 24+pos(not_idx[i] in leftover)
template <int P, int K, int SRCM, int EPIM, int QBASE>
__global__ __launch_bounds__(256, 2)
void fused_gemm(const float* __restrict__ fv,
                const unsigned short* __restrict__ Abf,
                const int* __restrict__ idx,
                const unsigned short* __restrict__ WT,   // bf16 W^T [512][K]
                const float* __restrict__ bias,
                unsigned short* __restrict__ hid_out,
                float* __restrict__ out,
                const int* __restrict__ leftover_idx) {
    constexpr int BM = 128, BN = 128, BK = 32;
    __shared__ unsigned short As[BM * BK];   // [m][k]
    __shared__ unsigned short Bs[BN * BK];   // [n][k]  (W^T tile)

    const int tid  = threadIdx.x;
    const int tm   = blockIdx.x * BM, tn = blockIdx.y * BN;
    const int lane = tid & 63, wave = tid >> 6;
    const int wm   = (wave & 1) * 64, wn = (wave >> 1) * 64;

    f32x4 acc[4][4];
    #pragma unroll
    for (int i = 0; i < 4; i++)
        #pragma unroll
        for (int j = 0; j < 4; j++)
            acc[i][j] = f32x4{0.f, 0.f, 0.f, 0.f};

    // staging: thread -> (row sr, 16-element chunk sc)
    const int sr = tid >> 1;
    const int sc = (tid & 1) * 16;

    const float* arow0 = nullptr;
    const float* arow1 = nullptr;
    const unsigned short* abrow = nullptr;
    {
        const int m = tm + sr;
        if (SRCM == 0) {
            const int b = m / P, p = m % P;
            const int f0 = idx[2 * p], f1 = idx[2 * p + 1];
            arow0 = fv + ((size_t)b * 64 + f0) * 512;
            arow1 = fv + ((size_t)b * 64 + f1) * 512;
        } else if (SRCM == 1) {
            const int b = m >> 3, i = m & 7;
            arow0 = fv + ((size_t)b * 64 + idx[i]) * 512;
        } else {
            abrow = Abf + (size_t)m * K;
        }
    }
    const unsigned short* wrow = WT + (size_t)(tn + sr) * K;

    for (int k0 = 0; k0 < K; k0 += BK) {
        uint4 pa0, pa1;
        if (SRCM == 2) {
            pa0 = *(const uint4*)(abrow + k0 + sc);
            pa1 = *(const uint4*)(abrow + k0 + sc + 8);
        } else {
            const float* s = (SRCM == 0 && k0 >= 512) ? (arow1 + (k0 - 512) + sc)
                                                      : (arow0 + k0 + sc);
            const float4 v0 = *(const float4*)(s);
            const float4 v1 = *(const float4*)(s + 4);
            const float4 v2 = *(const float4*)(s + 8);
            const float4 v3 = *(const float4*)(s + 12);
            pa0.x = pk(v0.x, v0.y); pa0.y = pk(v0.z, v0.w);
            pa0.z = pk(v1.x, v1.y); pa0.w = pk(v1.z, v1.w);
            pa1.x = pk(v2.x, v2.y); pa1.y = pk(v2.z, v2.w);
            pa1.z = pk(v3.x, v3.y); pa1.w = pk(v3.z, v3.w);
        }
        const uint4 wb0 = *(const uint4*)(wrow + k0 + sc);
        const uint4 wb1 = *(const uint4*)(wrow + k0 + sc + 8);

        __syncthreads();  // prev iter's LDS reads done
        *(uint4*)&As[sr * BK + sc]     = pa0;
        *(uint4*)&As[sr * BK + sc + 8] = pa1;
        *(uint4*)&Bs[sr * BK + sc]     = wb0;
        *(uint4*)&Bs[sr * BK + sc + 8] = wb1;
        __syncthreads();

        bf16x8 af[4], bfr[4];
        #pragma unroll
        for (int mi = 0; mi < 4; mi++)
            af[mi] = *(const bf16x8*)&As[(wm + mi * 16 + (lane & 15)) * BK + (lane >> 4) * 8];
        #pragma unroll
        for (int ni = 0; ni < 4; ni++)
            bfr[ni] = *(const bf16x8*)&Bs[(wn + ni * 16 + (lane & 15)) * BK + (lane >> 4) * 8];
        #pragma unroll
        for (int mi = 0; mi < 4; mi++)
            #pragma unroll
            for (int ni = 0; ni < 4; ni++)
                acc[mi][ni] = __builtin_amdgcn_mfma_f32_16x16x32_bf16(
                    af[mi], bfr[ni], acc[mi][ni], 0, 0, 0);
    }

    // ---- epilogue ----
    const int col0 = tn + wn + (lane & 15);
    const int row0 = tm + wm + (lane >> 4) * 4;

    int qmap[8];
    if (EPIM == 2) {
        #pragma unroll
        for (int i = 0; i < 8; i++) {
            const int f = idx[i];
            int q = QBASE;
            for (int l = 0; l < 16; l++)
                if (leftover_idx[l] == f) q = 24 + l;
            qmap[i] = q;
        }
    }

    #pragma unroll
    for (int ni = 0; ni < 4; ni++) {
        const int n  = col0 + ni * 16;
        const float bv = bias[n];
        #pragma unroll
        for (int mi = 0; mi < 4; mi++) {
            const int rbase = row0 + mi * 16;
            #pragma unroll
            for (int j = 0; j < 4; j++) {
                const int m = rbase + j;
                float v = acc[mi][ni][j] + bv;
                if (EPIM == 0) {
                    v = v > 0.f ? v : 0.f;
                    hid_out[(size_t)m * 512 + n] = f2bf(v);
                } else if (EPIM == 1) {
                    const int b = m / P, p = m % P;
                    out[((size_t)b * 40 + QBASE + p) * 512 + n] = v;
                } else {
                    const int b = m >> 3, i = m & 7;
                    out[((size_t)b * 40 + qmap[i]) * 512 + n] = tanhf(v);
                }
            }
        }
    }
}

// ---------- launch ----------
extern "C" void kernel_launch(void* const* d_in, const int* in_sizes, int n_in,
                              void* d_out, int out_size, void* d_ws, size_t ws_size,
                              hipStream_t stream) {
    const float* fv       = (const float*)d_in[0];
    const float* and_W1   = (const float*)d_in[1];
    const float* and_b1   = (const float*)d_in[2];
    const float* and_W2   = (const float*)d_in[3];
    const float* and_b2   = (const float*)d_in[4];
    const float* or_W1    = (const float*)d_in[5];
    const float* or_b1    = (const float*)d_in[6];
    const float* or_W2    = (const float*)d_in[7];
    const float* or_b2    = (const float*)d_in[8];
    const float* not_W    = (const float*)d_in[9];
    const float* not_b    = (const float*)d_in[10];
    const int* not_idx    = (const int*)d_in[11];
    const int* and_pairs  = (const int*)d_in[12];
    const int* or_pairs   = (const int*)d_in[13];
    const int* leftover   = (const int*)d_in[14];
    float* out = (float*)d_out;
    char* ws = (char*)d_ws;

    // ws layout (bytes)
    unsigned short* and_W1T = (unsigned short*)(ws + 0);          // 512x1024 bf16 = 1 MB
    unsigned short* or_W1T  = (unsigned short*)(ws + 1048576);    // 1 MB
    unsigned short* and_W2T = (unsigned short*)(ws + 2097152);    // 512x512 = 0.5 MB
    unsigned short* or_W2T  = (unsigned short*)(ws + 2621440);
    unsigned short* not_WT  = (unsigned short*)(ws + 3145728);
    unsigned short* and_hid = (unsigned short*)(ws + 3670016);    // 16384x512 bf16 = 16 MB
    unsigned short* or_hid  = (unsigned short*)(ws + 20447232);   // 8192x512 bf16 = 8 MB
    // total: 28835840 B (~27.5 MB)

    // 1) transpose+convert the 5 weight matrices to bf16 W^T
    TPArgs tp;
    tp.src[0] = and_W1; tp.dst[0] = and_W1T; tp.K[0] = 1024; tp.N[0] = 512;
    tp.src[1] = or_W1;  tp.dst[1] = or_W1T;  tp.K[1] = 1024; tp.N[1] = 512;
    tp.src[2] = and_W2; tp.dst[2] = and_W2T; tp.K[2] = 512;  tp.N[2] = 512;
    tp.src[3] = or_W2;  tp.dst[3] = or_W2T;  tp.K[3] = 512;  tp.N[3] = 512;
    tp.src[4] = not_W;  tp.dst[4] = not_WT;  tp.K[4] = 512;  tp.N[4] = 512;
    tp.tstart[0] = 0;   tp.tstart[1] = 128; tp.tstart[2] = 256;
    tp.tstart[3] = 320; tp.tstart[4] = 384; tp.tstart[5] = 448;
    transpose_convert<<<dim3(448), dim3(256), 0, stream>>>(tp);

    // 2) leftover passthrough (q=24..39); not-GEMM overwrites q=24..31 after
    copy_leftover<<<dim3(8192), dim3(256), 0, stream>>>(fv, leftover, out);

    // 3) not: tanh(fv[:,not_idx] @ not_W + not_b) -> out slots via leftover map
    fused_gemm<8, 512, 1, 2, 24><<<dim3(64, 4), dim3(256), 0, stream>>>(
        fv, nullptr, not_idx, not_WT, not_b, nullptr, out, leftover);

    // 4) and: L1 (gather-cat, ReLU -> hidden bf16), L2 (-> out q=0..15)
    fused_gemm<16, 1024, 0, 0, 0><<<dim3(128, 4), dim3(256), 0, stream>>>(
        fv, nullptr, and_pairs, and_W1T, and_b1, and_hid, nullptr, nullptr);
    fused_gemm<16, 512, 2, 1, 0><<<dim3(128, 4), dim3(256), 0, stream>>>(
        nullptr, and_hid, nullptr, and_W2T, and_b2, nullptr, out, nullptr);

    // 5) or: L1, L2 (-> out q=16..23)
    fused_gemm<8, 1024, 0, 0, 0><<<dim3(64, 4), dim3(256), 0, stream>>>(
        fv, nullptr, or_pairs, or_W1T, or_b1, or_hid, nullptr, nullptr);
    fused_gemm<8, 512, 2, 1, 16><<<dim3(64, 4), dim3(256), 0, stream>>>(
        nullptr, or_hid, nullptr, or_W2T, or_b2, nullptr, out, nullptr);
}

// Round 2
// 376.326 us; speedup vs baseline: 1.0104x; 1.0104x over previous
//
#include <hip/hip_runtime.h>
#include <hip/hip_bf16.h>
#include <math.h>

// ---------- types ----------
typedef __attribute__((ext_vector_type(8))) __bf16 bf16x8;
typedef __attribute__((ext_vector_type(4))) float f32x4;

// fp32 -> bf16 round-to-nearest-even
__device__ __forceinline__ unsigned short f2bf(float f) {
    union { float f; unsigned u; } v; v.f = f;
    unsigned r = v.u + 0x7fffu + ((v.u >> 16) & 1u);
    return (unsigned short)(r >> 16);
}
// pack two fp32 into one dword of two bf16 (lo, hi)
__device__ __forceinline__ unsigned int pk(float a, float b) {
    union { float f; unsigned u; } x, y; x.f = a; y.f = b;
    unsigned ra = (x.u + 0x7fffu + ((x.u >> 16) & 1u)) >> 16;
    unsigned rb = (y.u + 0x7fffu + ((y.u >> 16) & 1u)) & 0xffff0000u;
    return ra | rb;
}

// async global->LDS, 16 B per lane; LDS dest = wave-uniform base + lane*16
__device__ __forceinline__ void gl2lds16(const unsigned short* g, unsigned short* l) {
    __builtin_amdgcn_global_load_lds(
        (const __attribute__((address_space(1))) unsigned int*)(g),
        (__attribute__((address_space(3))) unsigned int*)(l), 16, 0, 0);
}

// ---------- prep kernel: fv->bf16 convert | leftover copy | weight transposes ----------
// block ranges: [0,8192) convert, [8192,10240) leftover, [10240,10688) transpose
struct PrepArgs {
    const float* fv;            // [1024*64*512] fp32
    unsigned short* fvb;        // bf16 copy
    const int* lidx;            // leftover_idx[16]
    float* out;                 // [1024*40*512]
    const float* W[5];          // weight sources (row-major [K][N])
    unsigned short* WT[5];      // bf16 W^T [N][K]
    int K[5], N[5];
    int tstart[6];              // transpose tile ranges (local to transpose range)
};

__global__ __launch_bounds__(256) void prep_kernel(PrepArgs a) {
    __shared__ float tile[64][65];
    const int blk = blockIdx.x;
    const int tid = threadIdx.x;

    if (blk < 8192) {
        // fv fp32 -> bf16, 16 elements/thread
        const int t = blk * 256 + tid;
        const size_t base = (size_t)t * 16;
        const float4* s = (const float4*)(a.fv + base);
        const float4 v0 = s[0], v1 = s[1], v2 = s[2], v3 = s[3];
        uint4 o0, o1;
        o0.x = pk(v0.x, v0.y); o0.y = pk(v0.z, v0.w);
        o0.z = pk(v1.x, v1.y); o0.w = pk(v1.z, v1.w);
        o1.x = pk(v2.x, v2.y); o1.y = pk(v2.z, v2.w);
        o1.z = pk(v3.x, v3.y); o1.w = pk(v3.z, v3.w);
        *(uint4*)(a.fvb + base)     = o0;
        *(uint4*)(a.fvb + base + 8) = o1;
    } else if (blk < 10240) {
        // out[b, 24+l, :] = fv[b, lidx[l], :]; 16 floats/thread
        const int t = (blk - 8192) * 256 + tid;
        const int c = t & 31, l = (t >> 5) & 15, b = t >> 9;
        const float4* s = (const float4*)(a.fv + ((size_t)b * 64 + a.lidx[l]) * 512 + c * 16);
        float4* d = (float4*)(a.out + ((size_t)b * 40 + 24 + l) * 512 + c * 16);
        d[0] = s[0]; d[1] = s[1]; d[2] = s[2]; d[3] = s[3];
    } else {
        // weight transpose+convert: dst[n*K+k] = bf16(src[k*N+n]), 64x64 tiles
        const int bx = blk - 10240;
        int m = 0;
        while (bx >= a.tstart[m + 1]) m++;
        const float* src = a.W[m];
        unsigned short* dst = a.WT[m];
        const int K = a.K[m], N = a.N[m];
        const int t = bx - a.tstart[m];
        const int ntn = N >> 6;
        const int tk = t / ntn, tn = t % ntn;
        const int c = tid & 63, r0 = tid >> 6;
        #pragma unroll
        for (int r = r0; r < 64; r += 4)
            tile[r][c] = src[(size_t)(tk * 64 + r) * N + tn * 64 + c];
        __syncthreads();
        #pragma unroll
        for (int r = r0; r < 64; r += 4)
            dst[(size_t)(tn * 64 + r) * K + tk * 64 + c] = f2bf(tile[c][r]);
    }
}

// ---------- merged MFMA GEMM ----------
// C[M,512] = act(A[M,K] @ W[K,512] + bias), BM=BN=128, BK=32, 4 waves/block
// srcm: 0 = gather concat(fvb[b,idx[2p]], fvb[b,idx[2p+1]]) (m=b*P+p, K=1024)
//       1 = gather fvb[b, idx[i]] (m=b*8+i, K=512)
//       2 = plain bf16 A [M,K]
// epim: 0 = ReLU -> bf16 hid[m*512+n]
//       1 = +bias -> fp32 out[(b*40+qbase+p)*512+n]
//       2 = tanh  -> fp32 out[(b*40+q)*512+n], q = 24+pos(idx[i] in leftover)
struct GSeg {
    const unsigned short* A;
    const int* idx;
    const unsigned short* WT;
    const float* bias;
    unsigned short* hid_out;
    float* out;
    int K, P, srcm, epim, qbase;
};
struct GArgs {
    GSeg seg[3];
    int seg_start[4];
    const int* leftover;
};

__global__ __launch_bounds__(256, 2) void mlp_gemm(GArgs a) {
    __shared__ __align__(16) unsigned short As[128 * 32];
    __shared__ __align__(16) unsigned short Bs[128 * 32];

    const int blk = blockIdx.x;
    int si = 0;
    while (blk >= a.seg_start[si + 1]) si++;
    const GSeg s = a.seg[si];
    const int local = blk - a.seg_start[si];
    const int tm = (local >> 2) * 128, tn = (local & 3) * 128;

    const int tid  = threadIdx.x;
    const int lane = tid & 63, w = tid >> 6;
    const int K = s.K;

    // per-lane staging pointers: call c covers rows [w*32+c*16, +16), lane l ->
    // row lm=l>>2, k-chunk kin=(l&3)*8 (16 B); LDS dest base+l*16 matches [m][k] layout
    const int lm  = lane >> 2;
    const int kin = (lane & 3) * 8;
    const unsigned short* ar0[2];
    const unsigned short* ar1[2];
    const unsigned short* wp[2];
    #pragma unroll
    for (int c = 0; c < 2; c++) {
        const int m = tm + w * 32 + c * 16 + lm;
        if (s.srcm == 0) {
            const int b = m / s.P, p = m % s.P;
            ar0[c] = s.A + ((size_t)b * 64 + s.idx[2 * p]) * 512;
            ar1[c] = s.A + ((size_t)b * 64 + s.idx[2 * p + 1]) * 512;
        } else if (s.srcm == 1) {
            const int b = m >> 3, i = m & 7;
            ar0[c] = s.A + ((size_t)b * 64 + s.idx[i]) * 512;
            ar1[c] = ar0[c];
        } else {
            ar0[c] = s.A + (size_t)m * K;
            ar1[c] = ar0[c];
        }
        const int n = tn + w * 32 + c * 16 + lm;
        wp[c] = s.WT + (size_t)n * K;
    }

    f32x4 acc[4][4];
    #pragma unroll
    for (int i = 0; i < 4; i++)
        #pragma unroll
        for (int j = 0; j < 4; j++)
            acc[i][j] = f32x4{0.f, 0.f, 0.f, 0.f};

    const int wm = (w & 1) * 64, wn = (w >> 1) * 64;

    for (int k0 = 0; k0 < K; k0 += 32) {
        const int kk = k0 & 511;           // offset within one 512-wide field half
        const bool hi = (k0 >= 512);       // second half of concat (srcm 0 only)
        __syncthreads();                   // prev iter's LDS reads done
        #pragma unroll
        for (int c = 0; c < 2; c++) {
            const unsigned short* asrc = (hi ? ar1[c] : ar0[c]) + kk + kin;
            gl2lds16(asrc, &As[w * 1024 + c * 512]);
            gl2lds16(wp[c] + k0 + kin, &Bs[w * 1024 + c * 512]);
        }
        __syncthreads();                   // drains vmcnt -> LDS data visible

        bf16x8 af[4], bfr[4];
        #pragma unroll
        for (int mi = 0; mi < 4; mi++)
            af[mi] = *(const bf16x8*)&As[(wm + mi * 16 + (lane & 15)) * 32 + (lane >> 4) * 8];
        #pragma unroll
        for (int ni = 0; ni < 4; ni++)
            bfr[ni] = *(const bf16x8*)&Bs[(wn + ni * 16 + (lane & 15)) * 32 + (lane >> 4) * 8];
        #pragma unroll
        for (int mi = 0; mi < 4; mi++)
            #pragma unroll
            for (int ni = 0; ni < 4; ni++)
                acc[mi][ni] = __builtin_amdgcn_mfma_f32_16x16x32_bf16(
                    af[mi], bfr[ni], acc[mi][ni], 0, 0, 0);
    }

    // ---- epilogue ----
    const int col0 = tn + wn + (lane & 15);
    const int row0 = tm + wm + (lane >> 4) * 4;

    int qmap[8];
    if (s.epim == 2) {
        #pragma unroll
        for (int i = 0; i < 8; i++) {
            const int f = s.idx[i];
            int q = 24;
            for (int l = 0; l < 16; l++)
                if (a.leftover[l] == f) q = 24 + l;
            qmap[i] = q;
        }
    }

    #pragma unroll
    for (int ni = 0; ni < 4; ni++) {
        const int n  = col0 + ni * 16;
        const float bv = s.bias[n];
        #pragma unroll
        for (int mi = 0; mi < 4; mi++) {
            const int rbase = row0 + mi * 16;
            #pragma unroll
            for (int j = 0; j < 4; j++) {
                const int m = rbase + j;
                float v = acc[mi][ni][j] + bv;
                if (s.epim == 0) {
                    v = v > 0.f ? v : 0.f;
                    s.hid_out[(size_t)m * 512 + n] = f2bf(v);
                } else if (s.epim == 1) {
                    const int b = m / s.P, p = m % s.P;
                    s.out[((size_t)b * 40 + s.qbase + p) * 512 + n] = v;
                } else {
                    const int b = m >> 3, i = m & 7;
                    s.out[((size_t)b * 40 + qmap[i]) * 512 + n] = tanhf(v);
                }
            }
        }
    }
}

// ---------- launch ----------
extern "C" void kernel_launch(void* const* d_in, const int* in_sizes, int n_in,
                              void* d_out, int out_size, void* d_ws, size_t ws_size,
                              hipStream_t stream) {
    const float* fv       = (const float*)d_in[0];
    const float* and_W1   = (const float*)d_in[1];
    const float* and_b1   = (const float*)d_in[2];
    const float* and_W2   = (const float*)d_in[3];
    const float* and_b2   = (const float*)d_in[4];
    const float* or_W1    = (const float*)d_in[5];
    const float* or_b1    = (const float*)d_in[6];
    const float* or_W2    = (const float*)d_in[7];
    const float* or_b2    = (const float*)d_in[8];
    const float* not_W    = (const float*)d_in[9];
    const float* not_b    = (const float*)d_in[10];
    const int* not_idx    = (const int*)d_in[11];
    const int* and_pairs  = (const int*)d_in[12];
    const int* or_pairs   = (const int*)d_in[13];
    const int* leftover   = (const int*)d_in[14];
    float* out = (float*)d_out;
    char* ws = (char*)d_ws;

    // ws layout (bytes)
    unsigned short* fvb     = (unsigned short*)(ws);              // 64 MB bf16 fv
    unsigned short* and_W1T = (unsigned short*)(ws + 67108864);   // 1 MB
    unsigned short* or_W1T  = (unsigned short*)(ws + 68157440);   // 1 MB
    unsigned short* and_W2T = (unsigned short*)(ws + 69206016);   // 0.5 MB
    unsigned short* or_W2T  = (unsigned short*)(ws + 69730304);   // 0.5 MB
    unsigned short* not_WT  = (unsigned short*)(ws + 70254592);   // 0.5 MB
    unsigned short* and_hid = (unsigned short*)(ws + 70778880);   // 16 MB
    unsigned short* or_hid  = (unsigned short*)(ws + 87556096);   // 8 MB

    // 1) prep: convert fv, copy leftover, transpose weights (1 launch)
    PrepArgs pa;
    pa.fv = fv; pa.fvb = fvb; pa.lidx = leftover; pa.out = out;
    pa.W[0] = and_W1; pa.WT[0] = and_W1T; pa.K[0] = 1024; pa.N[0] = 512;
    pa.W[1] = or_W1;  pa.WT[1] = or_W1T;  pa.K[1] = 1024; pa.N[1] = 512;
    pa.W[2] = and_W2; pa.WT[2] = and_W2T; pa.K[2] = 512;  pa.N[2] = 512;
    pa.W[3] = or_W2;  pa.WT[3] = or_W2T;  pa.K[3] = 512;  pa.N[3] = 512;
    pa.W[4] = not_W;  pa.WT[4] = not_WT;  pa.K[4] = 512;  pa.N[4] = 512;
    pa.tstart[0] = 0;   pa.tstart[1] = 128; pa.tstart[2] = 256;
    pa.tstart[3] = 320; pa.tstart[4] = 384; pa.tstart[5] = 448;
    prep_kernel<<<dim3(10688), dim3(256), 0, stream>>>(pa);

    // 2) L1 phase: and-L1 (512 blk) + or-L1 (256) + not (256) in one launch
    GArgs g1;
    g1.leftover = leftover;
    g1.seg[0] = {fvb, and_pairs, and_W1T, and_b1, and_hid, nullptr, 1024, 16, 0, 0, 0};
    g1.seg[1] = {fvb, or_pairs,  or_W1T,  or_b1,  or_hid,  nullptr, 1024,  8, 0, 0, 0};
    g1.seg[2] = {fvb, not_idx,   not_WT,  not_b,  nullptr, out,      512,  8, 1, 2, 24};
    g1.seg_start[0] = 0; g1.seg_start[1] = 512; g1.seg_start[2] = 768; g1.seg_start[3] = 1024;
    mlp_gemm<<<dim3(1024), dim3(256), 0, stream>>>(g1);

    // 3) L2 phase: and-L2 (512 blk) + or-L2 (256) in one launch
    GArgs g2;
    g2.leftover = leftover;
    g2.seg[0] = {and_hid, nullptr, and_W2T, and_b2, nullptr, out, 512, 16, 2, 1, 0};
    g2.seg[1] = {or_hid,  nullptr, or_W2T,  or_b2,  nullptr, out, 512,  8, 2, 1, 16};
    g2.seg[2] = g2.seg[1];
    g2.seg_start[0] = 0; g2.seg_start[1] = 512; g2.seg_start[2] = 768; g2.seg_start[3] = 768;
    mlp_gemm<<<dim3(768), dim3(256), 0, stream>>>(g2);
}

// Round 3
// 342.950 us; speedup vs baseline: 1.1088x; 1.0973x over previous
//
#include <hip/hip_runtime.h>
#include <hip/hip_bf16.h>
#include <math.h>

// ---------- types ----------
typedef __attribute__((ext_vector_type(8))) __bf16 bf16x8;
typedef __attribute__((ext_vector_type(4))) float f32x4;

// fp32 -> bf16 round-to-nearest-even
__device__ __forceinline__ unsigned short f2bf(float f) {
    union { float f; unsigned u; } v; v.f = f;
    unsigned r = v.u + 0x7fffu + ((v.u >> 16) & 1u);
    return (unsigned short)(r >> 16);
}
// pack two fp32 into one dword of two bf16 (lo, hi)
__device__ __forceinline__ unsigned int pk(float a, float b) {
    union { float f; unsigned u; } x, y; x.f = a; y.f = b;
    unsigned ra = (x.u + 0x7fffu + ((x.u >> 16) & 1u)) >> 16;
    unsigned rb = (y.u + 0x7fffu + ((y.u >> 16) & 1u)) & 0xffff0000u;
    return ra | rb;
}

// async global->LDS, 16 B per lane; LDS dest = wave-uniform base + lane*16
__device__ __forceinline__ void gl2lds16(const unsigned short* g, unsigned short* l) {
    __builtin_amdgcn_global_load_lds(
        (const __attribute__((address_space(1))) unsigned int*)(g),
        (__attribute__((address_space(3))) unsigned int*)(l), 16, 0, 0);
}

// ---------- prep kernel ----------
// [0,16384): fv fp32->bf16, lane-contiguous (2x float4 load, 1x uint4 store)
// [16384,24576): leftover copy out[b,24+l,:] = fv[b,lidx[l],:], 1 float4/thread
// [24576,25024): weight transpose+convert, 64x64 LDS tiles
struct PrepArgs {
    const float* fv;
    unsigned short* fvb;
    const int* lidx;
    float* out;
    const float* W[5];
    unsigned short* WT[5];
    int K[5], N[5];
    int tstart[6];
};

__global__ __launch_bounds__(256) void prep_kernel(PrepArgs a) {
    __shared__ float tile[64][65];
    const int blk = blockIdx.x;
    const int tid = threadIdx.x;

    if (blk < 16384) {
        const int t = blk * 256 + tid;          // 8 floats/thread, lane-contiguous
        const float4* s = (const float4*)a.fv;
        const float4 v0 = s[2 * (size_t)t];
        const float4 v1 = s[2 * (size_t)t + 1];
        uint4 o;
        o.x = pk(v0.x, v0.y); o.y = pk(v0.z, v0.w);
        o.z = pk(v1.x, v1.y); o.w = pk(v1.z, v1.w);
        ((uint4*)a.fvb)[t] = o;
    } else if (blk < 24576) {
        const int t = (blk - 16384) * 256 + tid;  // one float4, lane-contiguous
        const int c4 = t & 127, l = (t >> 7) & 15, b = t >> 11;
        const float4 v = *(const float4*)(a.fv + ((size_t)b * 64 + a.lidx[l]) * 512 + c4 * 4);
        *(float4*)(a.out + ((size_t)b * 40 + 24 + l) * 512 + c4 * 4) = v;
    } else {
        const int bx = blk - 24576;
        int m = 0;
        while (bx >= a.tstart[m + 1]) m++;
        const float* src = a.W[m];
        unsigned short* dst = a.WT[m];
        const int K = a.K[m], N = a.N[m];
        const int t = bx - a.tstart[m];
        const int ntn = N >> 6;
        const int tk = t / ntn, tn = t % ntn;
        const int c = tid & 63, r0 = tid >> 6;
        #pragma unroll
        for (int r = r0; r < 64; r += 4)
            tile[r][c] = src[(size_t)(tk * 64 + r) * N + tn * 64 + c];
        __syncthreads();
        #pragma unroll
        for (int r = r0; r < 64; r += 4)
            dst[(size_t)(tn * 64 + r) * K + tk * 64 + c] = f2bf(tile[c][r]);
    }
}

// ---------- templated GEMM segment (compile-time P/K/SRCM/EPIM/QBASE) ----------
// C[M,512] = act(A[M,K] @ W[K,512] + bias); BM=BN=128, BK=32, 4 waves/block
// SRCM: 0 = A row m = concat(fvb[b,idx[2p]], fvb[b,idx[2p+1]]), m=b*P+p, K=1024
//       1 = A row m = fvb[b, idx[i]], m=b*8+i
//       2 = plain bf16 A [M,K]
// EPIM: 0 = ReLU -> bf16 hid[m*512+n]
//       1 = +bias -> fp32 out[(b*40+QBASE+p)*512+n]
//       2 = tanh  -> fp32 out[(b*40+q)*512+n], q = 24+pos(idx[i] in leftover)
template <int P, int K, int SRCM, int EPIM, int QBASE>
__device__ __forceinline__ void gemm_seg(
    const unsigned short* __restrict__ A,
    const int* __restrict__ idx,
    const unsigned short* __restrict__ WT,
    const float* __restrict__ bias,
    unsigned short* __restrict__ hid_out,
    float* __restrict__ out,
    const int* __restrict__ leftover,
    int local,
    unsigned short* As, unsigned short* Bs) {

    const int tid  = threadIdx.x;
    const int lane = tid & 63, w = tid >> 6;
    const int tm = (local >> 2) * 128, tn = (local & 3) * 128;

    // staging: call c covers rows [w*32+c*16, +16); lane l -> row l>>2, k-chunk (l&3)*8
    const int lm  = lane >> 2;
    const int kin = (lane & 3) * 8;
    const unsigned short* ar0[2];
    const unsigned short* ar1[2];
    const unsigned short* wp[2];
    #pragma unroll
    for (int c = 0; c < 2; c++) {
        const int m = tm + w * 32 + c * 16 + lm;
        if constexpr (SRCM == 0) {
            const int b = m / P, p = m % P;
            ar0[c] = A + ((size_t)b * 64 + idx[2 * p]) * 512;
            ar1[c] = A + ((size_t)b * 64 + idx[2 * p + 1]) * 512;
        } else if constexpr (SRCM == 1) {
            const int b = m >> 3, i = m & 7;
            ar0[c] = A + ((size_t)b * 64 + idx[i]) * 512;
        } else {
            ar0[c] = A + (size_t)m * K;
        }
        const int n = tn + w * 32 + c * 16 + lm;
        wp[c] = WT + (size_t)n * K;
    }

    f32x4 acc[4][4];
    #pragma unroll
    for (int i = 0; i < 4; i++)
        #pragma unroll
        for (int j = 0; j < 4; j++)
            acc[i][j] = f32x4{0.f, 0.f, 0.f, 0.f};

    const int wm = (w & 1) * 64, wn = (w >> 1) * 64;

    for (int k0 = 0; k0 < K; k0 += 32) {
        __syncthreads();                   // prev iter's LDS reads done
        #pragma unroll
        for (int c = 0; c < 2; c++) {
            const unsigned short* asrc;
            if constexpr (SRCM == 0)
                asrc = (k0 >= 512 ? ar1[c] + (k0 - 512) : ar0[c] + k0) + kin;
            else
                asrc = ar0[c] + k0 + kin;
            gl2lds16(asrc, &As[w * 1024 + c * 512]);
            gl2lds16(wp[c] + k0 + kin, &Bs[w * 1024 + c * 512]);
        }
        __syncthreads();                   // vmcnt drained -> LDS visible

        bf16x8 af[4], bfr[4];
        #pragma unroll
        for (int mi = 0; mi < 4; mi++)
            af[mi] = *(const bf16x8*)&As[(wm + mi * 16 + (lane & 15)) * 32 + (lane >> 4) * 8];
        #pragma unroll
        for (int ni = 0; ni < 4; ni++)
            bfr[ni] = *(const bf16x8*)&Bs[(wn + ni * 16 + (lane & 15)) * 32 + (lane >> 4) * 8];
        #pragma unroll
        for (int mi = 0; mi < 4; mi++)
            #pragma unroll
            for (int ni = 0; ni < 4; ni++)
                acc[mi][ni] = __builtin_amdgcn_mfma_f32_16x16x32_bf16(
                    af[mi], bfr[ni], acc[mi][ni], 0, 0, 0);
    }

    // ---- epilogue ----
    const int col0 = tn + wn + (lane & 15);
    const int row0 = tm + wm + (lane >> 4) * 4;

    int qmap[8];
    if constexpr (EPIM == 2) {
        #pragma unroll
        for (int i = 0; i < 8; i++) {
            const int f = idx[i];
            int q = 24;
            for (int l = 0; l < 16; l++)
                if (leftover[l] == f) q = 24 + l;
            qmap[i] = q;
        }
    }

    #pragma unroll
    for (int ni = 0; ni < 4; ni++) {
        const int n  = col0 + ni * 16;
        const float bv = bias[n];
        #pragma unroll
        for (int mi = 0; mi < 4; mi++) {
            const int rbase = row0 + mi * 16;
            #pragma unroll
            for (int j = 0; j < 4; j++) {
                const int m = rbase + j;
                float v = acc[mi][ni][j] + bv;
                if constexpr (EPIM == 0) {
                    v = v > 0.f ? v : 0.f;
                    hid_out[(size_t)m * 512 + n] = f2bf(v);
                } else if constexpr (EPIM == 1) {
                    const int b = m / P, p = m % P;   // P constexpr -> shifts
                    out[((size_t)b * 40 + QBASE + p) * 512 + n] = v;
                } else {
                    const int b = m >> 3, i = m & 7;
                    out[((size_t)b * 40 + qmap[i]) * 512 + n] = tanhf(v);
                }
            }
        }
    }
}

// ---------- phase kernels ----------
struct L1Args {
    const unsigned short *fvb, *and_W1T, *or_W1T, *not_WT;
    const int *and_pairs, *or_pairs, *not_idx, *leftover;
    const float *and_b1, *or_b1, *not_b;
    unsigned short *and_hid, *or_hid;
    float* out;
};

__global__ __launch_bounds__(256, 3) void l1_phase(L1Args a) {
    __shared__ __align__(16) unsigned short As[128 * 32];
    __shared__ __align__(16) unsigned short Bs[128 * 32];
    const int blk = blockIdx.x;
    if (blk < 512)        // and-L1: M=16384, K=1024 -> hid
        gemm_seg<16, 1024, 0, 0, 0>(a.fvb, a.and_pairs, a.and_W1T, a.and_b1,
                                    a.and_hid, nullptr, nullptr, blk, As, Bs);
    else if (blk < 768)   // or-L1: M=8192, K=1024 -> hid
        gemm_seg<8, 1024, 0, 0, 0>(a.fvb, a.or_pairs, a.or_W1T, a.or_b1,
                                   a.or_hid, nullptr, nullptr, blk - 512, As, Bs);
    else                  // not: M=8192, K=512, tanh -> out
        gemm_seg<8, 512, 1, 2, 24>(a.fvb, a.not_idx, a.not_WT, a.not_b,
                                   nullptr, a.out, a.leftover, blk - 768, As, Bs);
}

struct L2Args {
    const unsigned short *and_hid, *or_hid, *and_W2T, *or_W2T;
    const float *and_b2, *or_b2;
    float* out;
};

__global__ __launch_bounds__(256, 3) void l2_phase(L2Args a) {
    __shared__ __align__(16) unsigned short As[128 * 32];
    __shared__ __align__(16) unsigned short Bs[128 * 32];
    const int blk = blockIdx.x;
    if (blk < 512)        // and-L2 -> out q=0..15
        gemm_seg<16, 512, 2, 1, 0>(a.and_hid, nullptr, a.and_W2T, a.and_b2,
                                   nullptr, a.out, nullptr, blk, As, Bs);
    else                  // or-L2 -> out q=16..23
        gemm_seg<8, 512, 2, 1, 16>(a.or_hid, nullptr, a.or_W2T, a.or_b2,
                                   nullptr, a.out, nullptr, blk - 512, As, Bs);
}

// ---------- launch ----------
extern "C" void kernel_launch(void* const* d_in, const int* in_sizes, int n_in,
                              void* d_out, int out_size, void* d_ws, size_t ws_size,
                              hipStream_t stream) {
    const float* fv       = (const float*)d_in[0];
    const float* and_W1   = (const float*)d_in[1];
    const float* and_b1   = (const float*)d_in[2];
    const float* and_W2   = (const float*)d_in[3];
    const float* and_b2   = (const float*)d_in[4];
    const float* or_W1    = (const float*)d_in[5];
    const float* or_b1    = (const float*)d_in[6];
    const float* or_W2    = (const float*)d_in[7];
    const float* or_b2    = (const float*)d_in[8];
    const float* not_W    = (const float*)d_in[9];
    const float* not_b    = (const float*)d_in[10];
    const int* not_idx    = (const int*)d_in[11];
    const int* and_pairs  = (const int*)d_in[12];
    const int* or_pairs   = (const int*)d_in[13];
    const int* leftover   = (const int*)d_in[14];
    float* out = (float*)d_out;
    char* ws = (char*)d_ws;

    // ws layout (bytes)
    unsigned short* fvb     = (unsigned short*)(ws);              // 64 MB bf16 fv
    unsigned short* and_W1T = (unsigned short*)(ws + 67108864);   // 1 MB
    unsigned short* or_W1T  = (unsigned short*)(ws + 68157440);   // 1 MB
    unsigned short* and_W2T = (unsigned short*)(ws + 69206016);   // 0.5 MB
    unsigned short* or_W2T  = (unsigned short*)(ws + 69730304);   // 0.5 MB
    unsigned short* not_WT  = (unsigned short*)(ws + 70254592);   // 0.5 MB
    unsigned short* and_hid = (unsigned short*)(ws + 70778880);   // 16 MB
    unsigned short* or_hid  = (unsigned short*)(ws + 87556096);   // 8 MB

    PrepArgs pa;
    pa.fv = fv; pa.fvb = fvb; pa.lidx = leftover; pa.out = out;
    pa.W[0] = and_W1; pa.WT[0] = and_W1T; pa.K[0] = 1024; pa.N[0] = 512;
    pa.W[1] = or_W1;  pa.WT[1] = or_W1T;  pa.K[1] = 1024; pa.N[1] = 512;
    pa.W[2] = and_W2; pa.WT[2] = and_W2T; pa.K[2] = 512;  pa.N[2] = 512;
    pa.W[3] = or_W2;  pa.WT[3] = or_W2T;  pa.K[3] = 512;  pa.N[3] = 512;
    pa.W[4] = not_W;  pa.WT[4] = not_WT;  pa.K[4] = 512;  pa.N[4] = 512;
    pa.tstart[0] = 0;   pa.tstart[1] = 128; pa.tstart[2] = 256;
    pa.tstart[3] = 320; pa.tstart[4] = 384; pa.tstart[5] = 448;
    prep_kernel<<<dim3(25024), dim3(256), 0, stream>>>(pa);

    L1Args g1;
    g1.fvb = fvb; g1.and_W1T = and_W1T; g1.or_W1T = or_W1T; g1.not_WT = not_WT;
    g1.and_pairs = and_pairs; g1.or_pairs = or_pairs; g1.not_idx = not_idx;
    g1.leftover = leftover;
    g1.and_b1 = and_b1; g1.or_b1 = or_b1; g1.not_b = not_b;
    g1.and_hid = and_hid; g1.or_hid = or_hid; g1.out = out;
    l1_phase<<<dim3(1024), dim3(256), 0, stream>>>(g1);

    L2Args g2;
    g2.and_hid = and_hid; g2.or_hid = or_hid;
    g2.and_W2T = and_W2T; g2.or_W2T = or_W2T;
    g2.and_b2 = and_b2; g2.or_b2 = or_b2; g2.out = out;
    l2_phase<<<dim3(768), dim3(256), 0, stream>>>(g2);
}

// Round 4
// 342.644 us; speedup vs baseline: 1.1098x; 1.0009x over previous
//
#include <hip/hip_runtime.h>
#include <hip/hip_bf16.h>
#include <math.h>

// ---------- types ----------
typedef __attribute__((ext_vector_type(8))) __bf16 bf16x8;
typedef __attribute__((ext_vector_type(4))) float f32x4;

// fp32 -> bf16 round-to-nearest-even
__device__ __forceinline__ unsigned short f2bf(float f) {
    union { float f; unsigned u; } v; v.f = f;
    unsigned r = v.u + 0x7fffu + ((v.u >> 16) & 1u);
    return (unsigned short)(r >> 16);
}
// pack two fp32 into one dword of two bf16 (lo, hi)
__device__ __forceinline__ unsigned int pk(float a, float b) {
    union { float f; unsigned u; } x, y; x.f = a; y.f = b;
    unsigned ra = (x.u + 0x7fffu + ((x.u >> 16) & 1u)) >> 16;
    unsigned rb = (y.u + 0x7fffu + ((y.u >> 16) & 1u)) & 0xffff0000u;
    return ra | rb;
}

// async global->LDS, 16 B per lane; LDS dest = wave-uniform base + lane*16
__device__ __forceinline__ void gl2lds16(const unsigned short* g, unsigned short* l) {
    __builtin_amdgcn_global_load_lds(
        (const __attribute__((address_space(1))) unsigned int*)(g),
        (__attribute__((address_space(3))) unsigned int*)(l), 16, 0, 0);
}

// ---------- prep kernel ----------
// [0,16384): fv fp32->bf16 for used fields + fp32 leftover passthrough to out
//            (one wave spans exactly one field row -> wave-uniform branches)
// [16384,16832): weight transpose+convert, 64x64 LDS tiles
struct PrepArgs {
    const float* fv;
    unsigned short* fvb;
    const int *and_pairs, *or_pairs, *not_idx, *lidx;
    float* out;
    const float* W[5];
    unsigned short* WT[5];
    int K[5], N[5];
    int tstart[6];
};

__global__ __launch_bounds__(256) void prep_kernel(PrepArgs a) {
    __shared__ float tile[64][65];
    __shared__ int used[64];
    __shared__ int lslot[64];
    const int blk = blockIdx.x;
    const int tid = threadIdx.x;

    if (blk < 16384) {
        // membership tables (per block, cheap)
        if (tid < 64) {
            const int f = tid;
            int u = 0;
            for (int i = 0; i < 32; i++) u |= (a.and_pairs[i] == f);
            for (int i = 0; i < 16; i++) u |= (a.or_pairs[i] == f);
            for (int i = 0; i < 8; i++)  u |= (a.not_idx[i] == f);
            used[f] = u;
            int ls = -1;
            for (int l = 0; l < 16; l++) if (a.lidx[l] == f) ls = l;
            lslot[f] = ls;
        }
        __syncthreads();

        const int t = blk * 256 + tid;     // 8 consecutive floats
        const size_t e = (size_t)t * 8;
        const int c = (int)(e & 511);
        const int f = (int)((e >> 9) & 63);
        const int b = (int)(e >> 15);
        const int u = used[f], ls = lslot[f];   // wave-uniform
        if (u | (ls >= 0)) {
            const float4 v0 = *(const float4*)(a.fv + e);
            const float4 v1 = *(const float4*)(a.fv + e + 4);
            if (u) {
                uint4 o;
                o.x = pk(v0.x, v0.y); o.y = pk(v0.z, v0.w);
                o.z = pk(v1.x, v1.y); o.w = pk(v1.z, v1.w);
                ((uint4*)a.fvb)[t] = o;
            }
            if (ls >= 0) {
                float* d = a.out + ((size_t)b * 40 + 24 + ls) * 512 + c;
                *(float4*)(d)     = v0;
                *(float4*)(d + 4) = v1;
            }
        }
    } else {
        const int bx = blk - 16384;
        int m = 0;
        while (bx >= a.tstart[m + 1]) m++;
        const float* src = a.W[m];
        unsigned short* dst = a.WT[m];
        const int K = a.K[m], N = a.N[m];
        const int t = bx - a.tstart[m];
        const int ntn = N >> 6;
        const int tk = t / ntn, tn = t % ntn;
        const int c = tid & 63, r0 = tid >> 6;
        #pragma unroll
        for (int r = r0; r < 64; r += 4)
            tile[r][c] = src[(size_t)(tk * 64 + r) * N + tn * 64 + c];
        __syncthreads();
        #pragma unroll
        for (int r = r0; r < 64; r += 4)
            dst[(size_t)(tn * 64 + r) * K + tk * 64 + c] = f2bf(tile[c][r]);
    }
}

// ---------- templated GEMM segment ----------
// C[M,512] = act(A[M,K] @ W[K,512] + bias); BM=BN=128, BK=32, 4 waves/block
// LDS layout XOR-swizzled: 16B-chunk slot cp of row r holds k-chunk cp^(r&3);
// staged by permuting each lane's global source chunk (dest is base+lane*16);
// frag reads use chunk (lane>>4)^(lane&3)  ->  conflict-free (2-way max).
// SRCM: 0 = A row m = concat(fvb[b,idx[2p]], fvb[b,idx[2p+1]]), m=b*P+p, K=1024
//       1 = A row m = fvb[b, idx[i]], m=b*8+i
//       2 = plain bf16 A [M,K]
// EPIM: 0 = ReLU -> bf16 hid[m*512+n]
//       1 = +bias -> fp32 out[(b*40+QBASE+p)*512+n]
//       2 = tanh  -> fp32 out[(b*40+q)*512+n], q = 24+pos(idx[i] in leftover)
template <int P, int K, int SRCM, int EPIM, int QBASE>
__device__ __forceinline__ void gemm_seg(
    const unsigned short* __restrict__ A,
    const int* __restrict__ idx,
    const unsigned short* __restrict__ WT,
    const float* __restrict__ bias,
    unsigned short* __restrict__ hid_out,
    float* __restrict__ out,
    const int* __restrict__ leftover,
    int local,
    unsigned short* As, unsigned short* Bs) {

    const int tid  = threadIdx.x;
    const int lane = tid & 63, w = tid >> 6;
    const int tm = (local >> 2) * 128, tn = (local & 3) * 128;

    // staging: call c covers rows [w*32+c*16, +16); lane l -> row l>>2,
    // swizzled source k-chunk ((l&3)^((l>>2)&3))*8 shorts (16 B)
    const int lm  = lane >> 2;
    const int kin = (((lane & 3) ^ ((lane >> 2) & 3)) * 8);
    const unsigned short* ar0[2];
    const unsigned short* ar1[2];
    const unsigned short* wp[2];
    #pragma unroll
    for (int c = 0; c < 2; c++) {
        const int m = tm + w * 32 + c * 16 + lm;
        if constexpr (SRCM == 0) {
            const int b = m / P, p = m % P;
            ar0[c] = A + ((size_t)b * 64 + idx[2 * p]) * 512;
            ar1[c] = A + ((size_t)b * 64 + idx[2 * p + 1]) * 512;
        } else if constexpr (SRCM == 1) {
            const int b = m >> 3, i = m & 7;
            ar0[c] = A + ((size_t)b * 64 + idx[i]) * 512;
        } else {
            ar0[c] = A + (size_t)m * K;
        }
        const int n = tn + w * 32 + c * 16 + lm;
        wp[c] = WT + (size_t)n * K;
    }

    f32x4 acc[4][4];
    #pragma unroll
    for (int i = 0; i < 4; i++)
        #pragma unroll
        for (int j = 0; j < 4; j++)
            acc[i][j] = f32x4{0.f, 0.f, 0.f, 0.f};

    const int wm = (w & 1) * 64, wn = (w >> 1) * 64;
    const int xsel = ((lane >> 4) ^ (lane & 3)) * 8;   // lane-constant frag chunk

    for (int k0 = 0; k0 < K; k0 += 32) {
        __syncthreads();                   // prev iter's LDS reads done
        #pragma unroll
        for (int c = 0; c < 2; c++) {
            const unsigned short* asrc;
            if constexpr (SRCM == 0)
                asrc = (k0 >= 512 ? ar1[c] + (k0 - 512) : ar0[c] + k0) + kin;
            else
                asrc = ar0[c] + k0 + kin;
            gl2lds16(asrc, &As[w * 1024 + c * 512]);
            gl2lds16(wp[c] + k0 + kin, &Bs[w * 1024 + c * 512]);
        }
        __syncthreads();                   // vmcnt drained -> LDS visible

        bf16x8 af[4], bfr[4];
        #pragma unroll
        for (int mi = 0; mi < 4; mi++)
            af[mi] = *(const bf16x8*)&As[(wm + mi * 16 + (lane & 15)) * 32 + xsel];
        #pragma unroll
        for (int ni = 0; ni < 4; ni++)
            bfr[ni] = *(const bf16x8*)&Bs[(wn + ni * 16 + (lane & 15)) * 32 + xsel];
        #pragma unroll
        for (int mi = 0; mi < 4; mi++)
            #pragma unroll
            for (int ni = 0; ni < 4; ni++)
                acc[mi][ni] = __builtin_amdgcn_mfma_f32_16x16x32_bf16(
                    af[mi], bfr[ni], acc[mi][ni], 0, 0, 0);
    }

    // ---- epilogue ----
    const int col0 = tn + wn + (lane & 15);
    const int row0 = tm + wm + (lane >> 4) * 4;

    int qmap[8];
    if constexpr (EPIM == 2) {
        #pragma unroll
        for (int i = 0; i < 8; i++) {
            const int f = idx[i];
            int q = 24;
            for (int l = 0; l < 16; l++)
                if (leftover[l] == f) q = 24 + l;
            qmap[i] = q;
        }
    }

    #pragma unroll
    for (int ni = 0; ni < 4; ni++) {
        const int n  = col0 + ni * 16;
        const float bv = bias[n];
        #pragma unroll
        for (int mi = 0; mi < 4; mi++) {
            const int rbase = row0 + mi * 16;
            #pragma unroll
            for (int j = 0; j < 4; j++) {
                const int m = rbase + j;
                float v = acc[mi][ni][j] + bv;
                if constexpr (EPIM == 0) {
                    v = v > 0.f ? v : 0.f;
                    hid_out[(size_t)m * 512 + n] = f2bf(v);
                } else if constexpr (EPIM == 1) {
                    const int b = m / P, p = m % P;   // P constexpr -> shifts
                    out[((size_t)b * 40 + QBASE + p) * 512 + n] = v;
                } else {
                    const int b = m >> 3, i = m & 7;
                    out[((size_t)b * 40 + qmap[i]) * 512 + n] = tanhf(v);
                }
            }
        }
    }
}

// ---------- phase kernels ----------
struct L1Args {
    const unsigned short *fvb, *and_W1T, *or_W1T, *not_WT;
    const int *and_pairs, *or_pairs, *not_idx, *leftover;
    const float *and_b1, *or_b1, *not_b;
    unsigned short *and_hid, *or_hid;
    float* out;
};

__global__ __launch_bounds__(256, 3) void l1_phase(L1Args a) {
    __shared__ __align__(16) unsigned short As[128 * 32];
    __shared__ __align__(16) unsigned short Bs[128 * 32];
    const int blk = blockIdx.x;
    if (blk < 512)        // and-L1: M=16384, K=1024 -> hid
        gemm_seg<16, 1024, 0, 0, 0>(a.fvb, a.and_pairs, a.and_W1T, a.and_b1,
                                    a.and_hid, nullptr, nullptr, blk, As, Bs);
    else if (blk < 768)   // or-L1: M=8192, K=1024 -> hid
        gemm_seg<8, 1024, 0, 0, 0>(a.fvb, a.or_pairs, a.or_W1T, a.or_b1,
                                   a.or_hid, nullptr, nullptr, blk - 512, As, Bs);
    else                  // not: M=8192, K=512, tanh -> out
        gemm_seg<8, 512, 1, 2, 24>(a.fvb, a.not_idx, a.not_WT, a.not_b,
                                   nullptr, a.out, a.leftover, blk - 768, As, Bs);
}

struct L2Args {
    const unsigned short *and_hid, *or_hid, *and_W2T, *or_W2T;
    const float *and_b2, *or_b2;
    float* out;
};

__global__ __launch_bounds__(256, 3) void l2_phase(L2Args a) {
    __shared__ __align__(16) unsigned short As[128 * 32];
    __shared__ __align__(16) unsigned short Bs[128 * 32];
    const int blk = blockIdx.x;
    if (blk < 512)        // and-L2 -> out q=0..15
        gemm_seg<16, 512, 2, 1, 0>(a.and_hid, nullptr, a.and_W2T, a.and_b2,
                                   nullptr, a.out, nullptr, blk, As, Bs);
    else                  // or-L2 -> out q=16..23
        gemm_seg<8, 512, 2, 1, 16>(a.or_hid, nullptr, a.or_W2T, a.or_b2,
                                   nullptr, a.out, nullptr, blk - 512, As, Bs);
}

// ---------- launch ----------
extern "C" void kernel_launch(void* const* d_in, const int* in_sizes, int n_in,
                              void* d_out, int out_size, void* d_ws, size_t ws_size,
                              hipStream_t stream) {
    const float* fv       = (const float*)d_in[0];
    const float* and_W1   = (const float*)d_in[1];
    const float* and_b1   = (const float*)d_in[2];
    const float* and_W2   = (const float*)d_in[3];
    const float* and_b2   = (const float*)d_in[4];
    const float* or_W1    = (const float*)d_in[5];
    const float* or_b1    = (const float*)d_in[6];
    const float* or_W2    = (const float*)d_in[7];
    const float* or_b2    = (const float*)d_in[8];
    const float* not_W    = (const float*)d_in[9];
    const float* not_b    = (const float*)d_in[10];
    const int* not_idx    = (const int*)d_in[11];
    const int* and_pairs  = (const int*)d_in[12];
    const int* or_pairs   = (const int*)d_in[13];
    const int* leftover   = (const int*)d_in[14];
    float* out = (float*)d_out;
    char* ws = (char*)d_ws;

    // ws layout (bytes)
    unsigned short* fvb     = (unsigned short*)(ws);              // 64 MB bf16 fv
    unsigned short* and_W1T = (unsigned short*)(ws + 67108864);   // 1 MB
    unsigned short* or_W1T  = (unsigned short*)(ws + 68157440);   // 1 MB
    unsigned short* and_W2T = (unsigned short*)(ws + 69206016);   // 0.5 MB
    unsigned short* or_W2T  = (unsigned short*)(ws + 69730304);   // 0.5 MB
    unsigned short* not_WT  = (unsigned short*)(ws + 70254592);   // 0.5 MB
    unsigned short* and_hid = (unsigned short*)(ws + 70778880);   // 16 MB
    unsigned short* or_hid  = (unsigned short*)(ws + 87556096);   // 8 MB

    PrepArgs pa;
    pa.fv = fv; pa.fvb = fvb; pa.out = out;
    pa.and_pairs = and_pairs; pa.or_pairs = or_pairs;
    pa.not_idx = not_idx; pa.lidx = leftover;
    pa.W[0] = and_W1; pa.WT[0] = and_W1T; pa.K[0] = 1024; pa.N[0] = 512;
    pa.W[1] = or_W1;  pa.WT[1] = or_W1T;  pa.K[1] = 1024; pa.N[1] = 512;
    pa.W[2] = and_W2; pa.WT[2] = and_W2T; pa.K[2] = 512;  pa.N[2] = 512;
    pa.W[3] = or_W2;  pa.WT[3] = or_W2T;  pa.K[3] = 512;  pa.N[3] = 512;
    pa.W[4] = not_W;  pa.WT[4] = not_WT;  pa.K[4] = 512;  pa.N[4] = 512;
    pa.tstart[0] = 0;   pa.tstart[1] = 128; pa.tstart[2] = 256;
    pa.tstart[3] = 320; pa.tstart[4] = 384; pa.tstart[5] = 448;
    prep_kernel<<<dim3(16832), dim3(256), 0, stream>>>(pa);

    L1Args g1;
    g1.fvb = fvb; g1.and_W1T = and_W1T; g1.or_W1T = or_W1T; g1.not_WT = not_WT;
    g1.and_pairs = and_pairs; g1.or_pairs = or_pairs; g1.not_idx = not_idx;
    g1.leftover = leftover;
    g1.and_b1 = and_b1; g1.or_b1 = or_b1; g1.not_b = not_b;
    g1.and_hid = and_hid; g1.or_hid = or_hid; g1.out = out;
    l1_phase<<<dim3(1024), dim3(256), 0, stream>>>(g1);

    L2Args g2;
    g2.and_hid = and_hid; g2.or_hid = or_hid;
    g2.and_W2T = and_W2T; g2.or_W2T = or_W2T;
    g2.and_b2 = and_b2; g2.or_b2 = or_b2; g2.out = out;
    l2_phase<<<dim3(768), dim3(256), 0, stream>>>(g2);
}